// Round 13
// baseline (232.673 us; speedup 1.0000x reference)
//
#include <hip/hip_runtime.h>
#include <hip/hip_bf16.h>

#define B_ 4
#define T_ 128
#define U_ 64
#define D_ 512
#define H_ 640
#define V_ 1024

typedef float f32x4 __attribute__((ext_vector_type(4)));

union U2L { uint2 u; long long l; };
union U4L2 { uint4 u; long long l[2]; };

// ---------------------------------------------------------------------------
// P0 fused prep:
//  blocks 0..95   : proj 8 rows each (bid<64: src->ps; 64..95: tgt->pt+b1)
//                   (8 rows/block halves the per-row W1 re-stream vs 4)
//  blocks 96..175 : pack W2 -> fp8 e4m3 fragment cells, column-permuted
//    (frag (kq,wid,nf,l16) holds original col wid*64 + l16*4 + nf).
//    uint2 cell at [kq*1024 + wid*64 + (nf>>1)*32 + l16*2 + (nf&1)].
// ---------------------------------------------------------------------------
__global__ __launch_bounds__(640) void k_prep(
    const float* __restrict__ W2, uint2* __restrict__ w2p8,
    const int* __restrict__ slen, const int* __restrict__ tlen,
    float* __restrict__ out_tail,
    const float* __restrict__ src, const float* __restrict__ tgt,
    const float* __restrict__ W1, const float* __restrict__ b1,
    float* __restrict__ ps, float* __restrict__ pt) {
  __shared__ __align__(16) float lin[D_ * 8];    // 16KB
  int bid = blockIdx.x, tid = threadIdx.x;
  if (bid < 96) {
    bool is_t = bid >= 64;
    int r0 = (is_t ? (bid - 64) : bid) * 8;
    const float* in = (is_t ? tgt : src) + (size_t)r0 * D_;
    const float* w = is_t ? (W1 + (size_t)D_ * H_) : W1;
    float* outp = (is_t ? pt : ps) + (size_t)r0 * H_;
    for (int idx = tid; idx < 8 * D_; idx += 640) {
      int r = idx >> 9, k = idx & (D_ - 1);
      lin[k * 8 + r] = in[idx];
    }
    __syncthreads();
    float a[8];
    #pragma unroll
    for (int r = 0; r < 8; ++r) a[r] = 0.f;
    int j = tid;
    for (int k = 0; k < D_; ++k) {
      float wv = w[(size_t)k * H_ + j];
      f32x4 x0 = *(const f32x4*)&lin[k * 8];
      f32x4 x1 = *(const f32x4*)&lin[k * 8 + 4];
      a[0] += x0[0] * wv; a[1] += x0[1] * wv;
      a[2] += x0[2] * wv; a[3] += x0[3] * wv;
      a[4] += x1[0] * wv; a[5] += x1[1] * wv;
      a[6] += x1[2] * wv; a[7] += x1[3] * wv;
    }
    float bb = is_t ? b1[j] : 0.f;
    #pragma unroll
    for (int r = 0; r < 8; ++r) outp[(size_t)r * H_ + j] = a[r] + bb;
  } else {
    int kq = bid - 96;             // 0..79
    for (int idx = tid; idx < V_; idx += 640) {
      int wid = idx >> 6, rem = idx & 63, nf = rem >> 4, l16 = rem & 15;
      int col = wid * 64 + l16 * 4 + nf;
      float f[8];
      #pragma unroll
      for (int j = 0; j < 8; ++j) f[j] = W2[(size_t)(kq * 8 + j) * V_ + col];
      int d0 = __builtin_amdgcn_cvt_pk_fp8_f32(f[0], f[1], 0, 0);
      d0 = __builtin_amdgcn_cvt_pk_fp8_f32(f[2], f[3], d0, 1);
      int d1 = __builtin_amdgcn_cvt_pk_fp8_f32(f[4], f[5], 0, 0);
      d1 = __builtin_amdgcn_cvt_pk_fp8_f32(f[6], f[7], d1, 1);
      uint2 c; c.x = (unsigned)d0; c.y = (unsigned)d1;
      w2p8[(size_t)kq * 1024 + wid * 64 + (nf >> 1) * 32 + l16 * 2 + (nf & 1)] = c;
    }
    if (bid == 96 && tid < 8)
      out_tail[tid] = (tid < 4) ? (float)slen[tid] : (float)tlen[tid - 4];
  }
}

// ---------------------------------------------------------------------------
// Main: 256 blocks (= exactly ONE residency round; reg file caps 16-wave
// blocks at 1/CU) x 1024 threads; each block does TWO t's sequentially.
// Phase-overlap rationale (R12 split showed K+epilogue ~= 72-76us is the
// wall): t0's nt-store drain + softmax tail now overlap t1's gen + K-loop
// within the same block, and there is no second grid round. fp8 makes this
// spill-safe where R4 (bf16) spilled: acc 64 + a 8 + B-prefetch 16+16
// transient + addr ~= 110 < 128-reg cap (FETCH/WRITE symmetric jump = spill
// canary). Depth-1 B prefetch hides ~200-400cy L2 latency per K-iter.
// ---------------------------------------------------------------------------
__global__ __launch_bounds__(1024, 4) void k_joint(
    const float* __restrict__ ps, const float* __restrict__ pt,
    const uint2* __restrict__ w2p8, const float* __restrict__ b2,
    float* __restrict__ out) {
  __shared__ uint2 ldsA[64 * 81];          // 41.5 KiB, [m][kq] padded rows
  __shared__ float red[16][64][2];         // 8 KiB
  __shared__ float lzs[64];
  int bid = blockIdx.x;                    // 0..255
  int xcd = bid & 7;
  int b = xcd >> 1;                        // one batch per XCD pair
  int t0 = ((bid >> 3) + (xcd & 1) * 32) * 2;   // 0,2,..,126
  int tid = threadIdx.x;
  int lane = tid & 63, wid = tid >> 6;     // wid 0..15
  int l16 = lane & 15, lg = lane >> 4;
  int gm = tid >> 4, gk = tid & 15;
  const float* ptrow = pt + (size_t)(b * U_ + gm) * H_;
  f32x4 b2v = *(const f32x4*)&b2[wid * 64 + l16 * 4];   // permuted cols
  const uint2* arow = ldsA + l16 * 81 + lg;
  const uint4* bp = (const uint4*)w2p8 + (size_t)lg * 512 + wid * 32 + l16;

  for (int ti = 0; ti < 2; ++ti) {
    int t = t0 + ti;
    const float* psrow = ps + (size_t)(b * T_ + t) * H_;

    // ---- phase 1: A generation -> fp8 LDS (overlaps prev ti's stores) ----
    {
      uint2* wrow = &ldsA[gm * 81];
      #pragma unroll
      for (int i = 0; i < 5; ++i) {
        int kq = i * 16 + gk;
        const float4* pp = (const float4*)(psrow + kq * 8);
        const float4* qq = (const float4*)(ptrow + kq * 8);
        float4 p0 = pp[0], p1 = pp[1];
        float4 q0 = qq[0], q1 = qq[1];
        float x[8] = {p0.x + q0.x, p0.y + q0.y, p0.z + q0.z, p0.w + q0.w,
                      p1.x + q1.x, p1.y + q1.y, p1.z + q1.z, p1.w + q1.w};
        float h[8];
        #pragma unroll
        for (int j = 0; j < 8; ++j) {
          float e = __expf(2.f * x[j]);
          h[j] = 1.f - 2.f * __builtin_amdgcn_rcpf(e + 1.f);
        }
        int d0 = __builtin_amdgcn_cvt_pk_fp8_f32(h[0], h[1], 0, 0);
        d0 = __builtin_amdgcn_cvt_pk_fp8_f32(h[2], h[3], d0, 1);
        int d1 = __builtin_amdgcn_cvt_pk_fp8_f32(h[4], h[5], 0, 0);
        d1 = __builtin_amdgcn_cvt_pk_fp8_f32(h[6], h[7], d1, 1);
        uint2 c; c.x = (unsigned)d0; c.y = (unsigned)d1;
        wrow[kq] = c;
      }
    }
    __syncthreads();

    f32x4 acc[4][4];
    #pragma unroll
    for (int mf = 0; mf < 4; ++mf)
      #pragma unroll
      for (int nf = 0; nf < 4; ++nf) {
        f32x4 z = {0.f, 0.f, 0.f, 0.f};
        acc[mf][nf] = z;
      }

    // ---- phase 2: K loop, fp8 MFMA, depth-1 B prefetch ----
    {
      U4L2 q0n, q1n;
      q0n.u = bp[0];
      q1n.u = bp[16];
      for (int kq0 = 0; kq0 < 80; kq0 += 4) {
        U4L2 q0 = q0n, q1 = q1n;
        if (kq0 < 76) {
          const uint4* bpn = bp + (size_t)(kq0 + 4) * 512;
          q0n.u = bpn[0];
          q1n.u = bpn[16];
        }
        U2L a[4];
        #pragma unroll
        for (int mf = 0; mf < 4; ++mf)
          a[mf].u = arow[mf * (16 * 81) + kq0];
        long long bbl[4] = {q0.l[0], q0.l[1], q1.l[0], q1.l[1]};
        #pragma unroll
        for (int nf = 0; nf < 4; ++nf)
          #pragma unroll
          for (int mf = 0; mf < 4; ++mf)
            acc[mf][nf] = __builtin_amdgcn_mfma_f32_16x16x32_fp8_fp8(
                a[mf].l, bbl[nf], acc[mf][nf], 0, 0, 0);
      }
    }

    // ---- phase 3: fold b2, two-level log_softmax, nt f32x4 store ----
    #pragma unroll
    for (int mf = 0; mf < 4; ++mf)
      #pragma unroll
      for (int nf = 0; nf < 4; ++nf)
        #pragma unroll
        for (int r = 0; r < 4; ++r)
          acc[mf][nf][r] += b2v[nf];

    #pragma unroll
    for (int mf = 0; mf < 4; ++mf)
      #pragma unroll
      for (int r = 0; r < 4; ++r) {
        float pm = -3.4e38f;
        #pragma unroll
        for (int nf = 0; nf < 4; ++nf) pm = fmaxf(pm, acc[mf][nf][r]);
        pm = fmaxf(pm, __shfl_xor(pm, 1));
        pm = fmaxf(pm, __shfl_xor(pm, 2));
        pm = fmaxf(pm, __shfl_xor(pm, 4));
        pm = fmaxf(pm, __shfl_xor(pm, 8));
        float s = 0.f;
        #pragma unroll
        for (int nf = 0; nf < 4; ++nf) s += __expf(acc[mf][nf][r] - pm);
        s += __shfl_xor(s, 1);
        s += __shfl_xor(s, 2);
        s += __shfl_xor(s, 4);
        s += __shfl_xor(s, 8);
        if (l16 == 0) {
          int row = mf * 16 + lg * 4 + r;
          red[wid][row][0] = pm;
          red[wid][row][1] = s;
        }
      }
    __syncthreads();

    if (tid < 64) {
      float M = -3.4e38f;
      #pragma unroll
      for (int w16 = 0; w16 < 16; ++w16) M = fmaxf(M, red[w16][tid][0]);
      float S = 0.f;
      #pragma unroll
      for (int w16 = 0; w16 < 16; ++w16)
        S += red[w16][tid][1] * __expf(red[w16][tid][0] - M);
      lzs[tid] = M + __logf(S);
    }
    __syncthreads();

    float* outb = out + (size_t)(b * T_ + t) * U_ * V_;
    #pragma unroll
    for (int mf = 0; mf < 4; ++mf)
      #pragma unroll
      for (int r = 0; r < 4; ++r) {
        int row = mf * 16 + lg * 4 + r;
        float lz = lzs[row];
        f32x4 o;
        o[0] = acc[mf][0][r] - lz;
        o[1] = acc[mf][1][r] - lz;
        o[2] = acc[mf][2][r] - lz;
        o[3] = acc[mf][3][r] - lz;
        __builtin_nontemporal_store(
            o, (f32x4*)&outb[(size_t)row * V_ + wid * 64 + l16 * 4]);
      }
    // nt stores drain under next ti's gen + K-loop
  }
}

extern "C" void kernel_launch(void* const* d_in, const int* in_sizes, int n_in,
                              void* d_out, int out_size, void* d_ws, size_t ws_size,
                              hipStream_t stream) {
  const float* src = (const float*)d_in[0];
  const int*   slen = (const int*)d_in[1];
  const float* tgt = (const float*)d_in[2];
  const int*   tlen = (const int*)d_in[3];
  const float* W1 = (const float*)d_in[4];
  const float* b1 = (const float*)d_in[5];
  const float* W2 = (const float*)d_in[6];
  const float* b2 = (const float*)d_in[7];
  float* out = (float*)d_out;

  float* ps   = (float*)d_ws;                 // 512*640 f32
  float* pt   = ps + 512 * 640;               // 256*640 f32
  uint2* w2p8 = (uint2*)(pt + 256 * 640);     // 80*1024 uint2 (fp8 W2)

  k_prep<<<176, 640, 0, stream>>>(W2, w2p8, slen, tlen,
                                  out + (size_t)B_ * T_ * U_ * V_,
                                  src, tgt, W1, b1, ps, pt);
  k_joint<<<256, 1024, 0, stream>>>(ps, pt, w2p8, b2, out);
}

// Round 14
// 119.129 us; speedup vs baseline: 1.9531x; 1.9531x over previous
//
#include <hip/hip_runtime.h>
#include <hip/hip_bf16.h>

#define B_ 4
#define T_ 128
#define U_ 64
#define D_ 512
#define H_ 640
#define V_ 1024

typedef float f32x4 __attribute__((ext_vector_type(4)));

union U2L { uint2 u; long long l; };
union U4L2 { uint4 u; long long l[2]; };

// ---------------------------------------------------------------------------
// P0 fused prep:
//  blocks 0..31  : proj src rows bid*16..+16 -> ps
//  blocks 32..47 : proj tgt rows (bid-32)*16 -> pt (+b1)
//    (16 rows/block: W1 streamed by 48 blocks = 63MB, was 168MB at 4 rows)
//  blocks 48..127: pack W2 -> fp8 e4m3 fragment cells, column-permuted
//    uint2 cell at [kq*1024 + wid*64 + (nf>>1)*32 + l16*2 + (nf&1)],
//    holding original col wid*64 + l16*4 + nf for k=8kq..8kq+7.
// ---------------------------------------------------------------------------
__global__ __launch_bounds__(640) void k_prep(
    const float* __restrict__ W2, uint2* __restrict__ w2p8,
    const int* __restrict__ slen, const int* __restrict__ tlen,
    float* __restrict__ out_tail,
    const float* __restrict__ src, const float* __restrict__ tgt,
    const float* __restrict__ W1, const float* __restrict__ b1,
    float* __restrict__ ps, float* __restrict__ pt) {
  __shared__ __align__(16) float lin[D_ * 16];   // 32KB
  int bid = blockIdx.x, tid = threadIdx.x;
  if (bid < 48) {
    bool is_t = bid >= 32;
    int r0 = (is_t ? (bid - 32) : bid) * 16;
    const float* in = (is_t ? tgt : src) + (size_t)r0 * D_;
    const float* w = is_t ? (W1 + (size_t)D_ * H_) : W1;
    float* outp = (is_t ? pt : ps) + (size_t)r0 * H_;
    for (int idx = tid; idx < 16 * D_; idx += 640) {
      int r = idx >> 9, k = idx & (D_ - 1);
      lin[k * 16 + r] = in[idx];
    }
    __syncthreads();
    float a[16];
    #pragma unroll
    for (int r = 0; r < 16; ++r) a[r] = 0.f;
    int j = tid;
    for (int k = 0; k < D_; ++k) {
      float wv = w[(size_t)k * H_ + j];
      const f32x4* x = (const f32x4*)&lin[k * 16];
      #pragma unroll
      for (int q = 0; q < 4; ++q) {
        f32x4 xv = x[q];
        a[q * 4 + 0] += xv[0] * wv;
        a[q * 4 + 1] += xv[1] * wv;
        a[q * 4 + 2] += xv[2] * wv;
        a[q * 4 + 3] += xv[3] * wv;
      }
    }
    float bb = is_t ? b1[j] : 0.f;
    #pragma unroll
    for (int r = 0; r < 16; ++r) outp[(size_t)r * H_ + j] = a[r] + bb;
  } else {
    int kq = bid - 48;             // 0..79
    for (int idx = tid; idx < V_; idx += 640) {
      int wid = idx >> 6, rem = idx & 63, nf = rem >> 4, l16 = rem & 15;
      int col = wid * 64 + l16 * 4 + nf;
      float f[8];
      #pragma unroll
      for (int j = 0; j < 8; ++j) f[j] = W2[(size_t)(kq * 8 + j) * V_ + col];
      int d0 = __builtin_amdgcn_cvt_pk_fp8_f32(f[0], f[1], 0, 0);
      d0 = __builtin_amdgcn_cvt_pk_fp8_f32(f[2], f[3], d0, 1);
      int d1 = __builtin_amdgcn_cvt_pk_fp8_f32(f[4], f[5], 0, 0);
      d1 = __builtin_amdgcn_cvt_pk_fp8_f32(f[6], f[7], d1, 1);
      uint2 c; c.x = (unsigned)d0; c.y = (unsigned)d1;
      w2p8[(size_t)kq * 1024 + wid * 64 + (nf >> 1) * 32 + l16 * 2 + (nf & 1)] = c;
    }
    if (bid == 48 && tid < 8)
      out_tail[tid] = (tid < 4) ? (float)slen[tid] : (float)tlen[tid - 4];
  }
}

// ---------------------------------------------------------------------------
// Main: 1024 blocks x 512 threads (8 waves) -- TWO blocks co-resident per CU
// (8 waves x ~110 regs x 2 blocks = 16 waves, full pool). R13 proved 16-wave
// blocks pin working VGPRs at 64 (acc takes the other 64 of the 128 cap) so
// intra-block pipelining always spills; instead, INTER-block overlap: when
// block A runs serial gen/softmax (VALU), block B's K-loop feeds MFMA.
// Block = 32 u-rows x full V (block-local softmax); wave owns 128 cols:
// acc[2][8]=64 regs, B loads die in-iter (no loop-carried state, no spill).
// ---------------------------------------------------------------------------
__global__ __launch_bounds__(512, 4) void k_joint(
    const float* __restrict__ ps, const float* __restrict__ pt,
    const uint2* __restrict__ w2p8, const float* __restrict__ b2,
    float* __restrict__ out) {
  __shared__ uint2 ldsA[32 * 81];          // 20.7 KiB, [m][kq] padded rows
  __shared__ float red[8][32][2];          // 1 KiB
  __shared__ float lzs[32];
  int bid = blockIdx.x;                    // 0..1023
  int xcd = bid & 7;
  int b = xcd >> 1;                        // one batch per XCD pair
  int rest = bid >> 3;                     // 0..127
  int t = (rest & 63) + (xcd & 1) * 64;    // 0..127
  int uh = rest >> 6;                      // u-half 0/1
  int tid = threadIdx.x;
  int lane = tid & 63, wid = tid >> 6;     // wid 0..7
  int l16 = lane & 15, lg = lane >> 4;
  const float* psrow = ps + (size_t)(b * T_ + t) * H_;

  // ---- phase 1: A generation -> fp8 LDS; thread owns row gm (0..31) ----
  {
    int gm = tid >> 4, gk = tid & 15;
    const float* ptrow = pt + (size_t)(b * U_ + uh * 32 + gm) * H_;
    uint2* wrow = &ldsA[gm * 81];
    #pragma unroll
    for (int i = 0; i < 5; ++i) {
      int kq = i * 16 + gk;
      const float4* pp = (const float4*)(psrow + kq * 8);
      const float4* qq = (const float4*)(ptrow + kq * 8);
      float4 p0 = pp[0], p1 = pp[1];
      float4 q0 = qq[0], q1 = qq[1];
      float x[8] = {p0.x + q0.x, p0.y + q0.y, p0.z + q0.z, p0.w + q0.w,
                    p1.x + q1.x, p1.y + q1.y, p1.z + q1.z, p1.w + q1.w};
      float h[8];
      #pragma unroll
      for (int j = 0; j < 8; ++j) {
        float e = __expf(2.f * x[j]);
        h[j] = 1.f - 2.f * __builtin_amdgcn_rcpf(e + 1.f);
      }
      int d0 = __builtin_amdgcn_cvt_pk_fp8_f32(h[0], h[1], 0, 0);
      d0 = __builtin_amdgcn_cvt_pk_fp8_f32(h[2], h[3], d0, 1);
      int d1 = __builtin_amdgcn_cvt_pk_fp8_f32(h[4], h[5], 0, 0);
      d1 = __builtin_amdgcn_cvt_pk_fp8_f32(h[6], h[7], d1, 1);
      uint2 c; c.x = (unsigned)d0; c.y = (unsigned)d1;
      wrow[kq] = c;
    }
  }
  __syncthreads();

  f32x4 acc[2][8];
  #pragma unroll
  for (int mf = 0; mf < 2; ++mf)
    #pragma unroll
    for (int nf = 0; nf < 8; ++nf) {
      f32x4 z = {0.f, 0.f, 0.f, 0.f};
      acc[mf][nf] = z;
    }

  // ---- phase 2: K loop (20 iters of K=32); wave owns cols wid*128.. ----
  {
    const uint2* arow = ldsA + l16 * 81 + lg;
    // col-block c0 = 2*wid, c1 = 2*wid+1 (64-col pack units)
    const uint4* bp = (const uint4*)w2p8 + (size_t)lg * 512 + l16;
    for (int kq0 = 0; kq0 < 80; kq0 += 4) {
      U2L a[2];
      #pragma unroll
      for (int mf = 0; mf < 2; ++mf)
        a[mf].u = arow[mf * (16 * 81) + kq0];
      const uint4* bpi = bp + (size_t)kq0 * 512 + wid * 64;
      U4L2 q[4];
      q[0].u = bpi[0];                 // cols c0, nf 0,1
      q[1].u = bpi[16];                // cols c0, nf 2,3
      q[2].u = bpi[32];                // cols c1, nf 0,1
      q[3].u = bpi[48];                // cols c1, nf 2,3
      #pragma unroll
      for (int nf = 0; nf < 8; ++nf) {
        long long bl = q[nf >> 1].l[nf & 1];
        #pragma unroll
        for (int mf = 0; mf < 2; ++mf)
          acc[mf][nf] = __builtin_amdgcn_mfma_f32_16x16x32_fp8_fp8(
              a[mf].l, bl, acc[mf][nf], 0, 0, 0);
      }
    }
  }

  // ---- phase 3: fold b2 (permuted within each 64-col block), softmax ----
  {
    f32x4 b2v0 = *(const f32x4*)&b2[wid * 128 + l16 * 4];
    f32x4 b2v1 = *(const f32x4*)&b2[wid * 128 + 64 + l16 * 4];
    #pragma unroll
    for (int mf = 0; mf < 2; ++mf)
      #pragma unroll
      for (int nf = 0; nf < 8; ++nf) {
        float bv = (nf < 4) ? b2v0[nf] : b2v1[nf - 4];
        #pragma unroll
        for (int r = 0; r < 4; ++r)
          acc[mf][nf][r] += bv;
      }
  }

  #pragma unroll
  for (int mf = 0; mf < 2; ++mf)
    #pragma unroll
    for (int r = 0; r < 4; ++r) {
      float pm = -3.4e38f;
      #pragma unroll
      for (int nf = 0; nf < 8; ++nf) pm = fmaxf(pm, acc[mf][nf][r]);
      pm = fmaxf(pm, __shfl_xor(pm, 1));
      pm = fmaxf(pm, __shfl_xor(pm, 2));
      pm = fmaxf(pm, __shfl_xor(pm, 4));
      pm = fmaxf(pm, __shfl_xor(pm, 8));
      float s = 0.f;
      #pragma unroll
      for (int nf = 0; nf < 8; ++nf) s += __expf(acc[mf][nf][r] - pm);
      s += __shfl_xor(s, 1);
      s += __shfl_xor(s, 2);
      s += __shfl_xor(s, 4);
      s += __shfl_xor(s, 8);
      if (l16 == 0) {
        int row = mf * 16 + lg * 4 + r;    // 0..31
        red[wid][row][0] = pm;
        red[wid][row][1] = s;
      }
    }
  __syncthreads();

  if (tid < 32) {
    float M = -3.4e38f;
    #pragma unroll
    for (int w8 = 0; w8 < 8; ++w8) M = fmaxf(M, red[w8][tid][0]);
    float S = 0.f;
    #pragma unroll
    for (int w8 = 0; w8 < 8; ++w8)
      S += red[w8][tid][1] * __expf(red[w8][tid][0] - M);
    lzs[tid] = M + __logf(S);
  }
  __syncthreads();

  float* outb = out + ((size_t)(b * T_ + t) * U_ + uh * 32) * V_;
  #pragma unroll
  for (int mf = 0; mf < 2; ++mf)
    #pragma unroll
    for (int r = 0; r < 4; ++r) {
      int row = mf * 16 + lg * 4 + r;
      float lz = lzs[row];
      f32x4 o0, o1;
      o0[0] = acc[mf][0][r] - lz;
      o0[1] = acc[mf][1][r] - lz;
      o0[2] = acc[mf][2][r] - lz;
      o0[3] = acc[mf][3][r] - lz;
      o1[0] = acc[mf][4][r] - lz;
      o1[1] = acc[mf][5][r] - lz;
      o1[2] = acc[mf][6][r] - lz;
      o1[3] = acc[mf][7][r] - lz;
      float* orow = outb + (size_t)row * V_ + wid * 128 + l16 * 4;
      __builtin_nontemporal_store(o0, (f32x4*)orow);
      __builtin_nontemporal_store(o1, (f32x4*)(orow + 64));
    }
}

extern "C" void kernel_launch(void* const* d_in, const int* in_sizes, int n_in,
                              void* d_out, int out_size, void* d_ws, size_t ws_size,
                              hipStream_t stream) {
  const float* src = (const float*)d_in[0];
  const int*   slen = (const int*)d_in[1];
  const float* tgt = (const float*)d_in[2];
  const int*   tlen = (const int*)d_in[3];
  const float* W1 = (const float*)d_in[4];
  const float* b1 = (const float*)d_in[5];
  const float* W2 = (const float*)d_in[6];
  const float* b2 = (const float*)d_in[7];
  float* out = (float*)d_out;

  float* ps   = (float*)d_ws;                 // 512*640 f32
  float* pt   = ps + 512 * 640;               // 256*640 f32
  uint2* w2p8 = (uint2*)(pt + 256 * 640);     // 80*1024 uint2 (fp8 W2)

  k_prep<<<128, 640, 0, stream>>>(W2, w2p8, slen, tlen,
                                  out + (size_t)B_ * T_ * U_ * V_,
                                  src, tgt, W1, b1, ps, pt);
  k_joint<<<1024, 512, 0, stream>>>(ps, pt, w2p8, b2, out);
}

// Round 15
// 94.009 us; speedup vs baseline: 2.4750x; 1.2672x over previous
//
#include <hip/hip_runtime.h>
#include <hip/hip_bf16.h>

#define B_ 4
#define T_ 128
#define U_ 64
#define D_ 512
#define H_ 640
#define V_ 1024

typedef float f32x4 __attribute__((ext_vector_type(4)));

union U2L { uint2 u; long long l; };
union U4L2 { uint4 u; long long l[2]; };

// ---------------------------------------------------------------------------
// P0 fused prep (R13 config, measured 8.5us):
//  blocks 0..95   : proj 8 rows each (bid<64: src->ps; 64..95: tgt->pt+b1)
//  blocks 96..175 : pack W2 -> fp8 e4m3 fragment cells, column-permuted
//    uint2 cell at [kq*1024 + wid*64 + (nf>>1)*32 + l16*2 + (nf&1)],
//    holding original col wid*64 + l16*4 + nf for k=8kq..8kq+7.
// NOTE (R14 lesson): 16 rows/block (48 proj blocks) regressed prep to 80us --
// a[16] register pressure stops the compiler pipelining the 512-iter loop,
// exposing ~400cy L2 latency per iter. 8 rows is the proven sweet spot.
// ---------------------------------------------------------------------------
__global__ __launch_bounds__(640) void k_prep(
    const float* __restrict__ W2, uint2* __restrict__ w2p8,
    const int* __restrict__ slen, const int* __restrict__ tlen,
    float* __restrict__ out_tail,
    const float* __restrict__ src, const float* __restrict__ tgt,
    const float* __restrict__ W1, const float* __restrict__ b1,
    float* __restrict__ ps, float* __restrict__ pt) {
  __shared__ __align__(16) float lin[D_ * 8];    // 16KB
  int bid = blockIdx.x, tid = threadIdx.x;
  if (bid < 96) {
    bool is_t = bid >= 64;
    int r0 = (is_t ? (bid - 64) : bid) * 8;
    const float* in = (is_t ? tgt : src) + (size_t)r0 * D_;
    const float* w = is_t ? (W1 + (size_t)D_ * H_) : W1;
    float* outp = (is_t ? pt : ps) + (size_t)r0 * H_;
    for (int idx = tid; idx < 8 * D_; idx += 640) {
      int r = idx >> 9, k = idx & (D_ - 1);
      lin[k * 8 + r] = in[idx];
    }
    __syncthreads();
    float a[8];
    #pragma unroll
    for (int r = 0; r < 8; ++r) a[r] = 0.f;
    int j = tid;
    for (int k = 0; k < D_; ++k) {
      float wv = w[(size_t)k * H_ + j];
      f32x4 x0 = *(const f32x4*)&lin[k * 8];
      f32x4 x1 = *(const f32x4*)&lin[k * 8 + 4];
      a[0] += x0[0] * wv; a[1] += x0[1] * wv;
      a[2] += x0[2] * wv; a[3] += x0[3] * wv;
      a[4] += x1[0] * wv; a[5] += x1[1] * wv;
      a[6] += x1[2] * wv; a[7] += x1[3] * wv;
    }
    float bb = is_t ? b1[j] : 0.f;
    #pragma unroll
    for (int r = 0; r < 8; ++r) outp[(size_t)r * H_ + j] = a[r] + bb;
  } else {
    int kq = bid - 96;             // 0..79
    for (int idx = tid; idx < V_; idx += 640) {
      int wid = idx >> 6, rem = idx & 63, nf = rem >> 4, l16 = rem & 15;
      int col = wid * 64 + l16 * 4 + nf;
      float f[8];
      #pragma unroll
      for (int j = 0; j < 8; ++j) f[j] = W2[(size_t)(kq * 8 + j) * V_ + col];
      int d0 = __builtin_amdgcn_cvt_pk_fp8_f32(f[0], f[1], 0, 0);
      d0 = __builtin_amdgcn_cvt_pk_fp8_f32(f[2], f[3], d0, 1);
      int d1 = __builtin_amdgcn_cvt_pk_fp8_f32(f[4], f[5], 0, 0);
      d1 = __builtin_amdgcn_cvt_pk_fp8_f32(f[6], f[7], d1, 1);
      uint2 c; c.x = (unsigned)d0; c.y = (unsigned)d1;
      w2p8[(size_t)kq * 1024 + wid * 64 + (nf >> 1) * 32 + l16 * 2 + (nf & 1)] = c;
    }
    if (bid == 96 && tid < 8)
      out_tail[tid] = (tid < 4) ? (float)slen[tid] : (float)tlen[tid - 4];
  }
}

// ---------------------------------------------------------------------------
// Main (R14 config, measured ~38us): 1024 blocks x 512 threads (8 waves) --
// TWO blocks co-resident per CU. Inter-block phase overlap: while block A
// runs serial gen/softmax (VALU), block B's K-loop feeds the MFMA pipe.
// Block = 32 u-rows x full V (block-local softmax); wave owns 128 cols:
// acc[2][8]=64 regs, B loads die in-iter (no loop-carried state, no spill --
// the R4/R13 register-ledger lesson).
// ---------------------------------------------------------------------------
__global__ __launch_bounds__(512, 4) void k_joint(
    const float* __restrict__ ps, const float* __restrict__ pt,
    const uint2* __restrict__ w2p8, const float* __restrict__ b2,
    float* __restrict__ out) {
  __shared__ uint2 ldsA[32 * 81];          // 20.7 KiB, [m][kq] padded rows
  __shared__ float red[8][32][2];          // 1 KiB
  __shared__ float lzs[32];
  int bid = blockIdx.x;                    // 0..1023
  int xcd = bid & 7;
  int b = xcd >> 1;                        // one batch per XCD pair
  int rest = bid >> 3;                     // 0..127
  int t = (rest & 63) + (xcd & 1) * 64;    // 0..127
  int uh = rest >> 6;                      // u-half 0/1
  int tid = threadIdx.x;
  int lane = tid & 63, wid = tid >> 6;     // wid 0..7
  int l16 = lane & 15, lg = lane >> 4;
  const float* psrow = ps + (size_t)(b * T_ + t) * H_;

  // ---- phase 1: A generation -> fp8 LDS; thread owns row gm (0..31) ----
  {
    int gm = tid >> 4, gk = tid & 15;
    const float* ptrow = pt + (size_t)(b * U_ + uh * 32 + gm) * H_;
    uint2* wrow = &ldsA[gm * 81];
    #pragma unroll
    for (int i = 0; i < 5; ++i) {
      int kq = i * 16 + gk;
      const float4* pp = (const float4*)(psrow + kq * 8);
      const float4* qq = (const float4*)(ptrow + kq * 8);
      float4 p0 = pp[0], p1 = pp[1];
      float4 q0 = qq[0], q1 = qq[1];
      float x[8] = {p0.x + q0.x, p0.y + q0.y, p0.z + q0.z, p0.w + q0.w,
                    p1.x + q1.x, p1.y + q1.y, p1.z + q1.z, p1.w + q1.w};
      float h[8];
      #pragma unroll
      for (int j = 0; j < 8; ++j) {
        float e = __expf(2.f * x[j]);
        h[j] = 1.f - 2.f * __builtin_amdgcn_rcpf(e + 1.f);
      }
      int d0 = __builtin_amdgcn_cvt_pk_fp8_f32(h[0], h[1], 0, 0);
      d0 = __builtin_amdgcn_cvt_pk_fp8_f32(h[2], h[3], d0, 1);
      int d1 = __builtin_amdgcn_cvt_pk_fp8_f32(h[4], h[5], 0, 0);
      d1 = __builtin_amdgcn_cvt_pk_fp8_f32(h[6], h[7], d1, 1);
      uint2 c; c.x = (unsigned)d0; c.y = (unsigned)d1;
      wrow[kq] = c;
    }
  }
  __syncthreads();

  f32x4 acc[2][8];
  #pragma unroll
  for (int mf = 0; mf < 2; ++mf)
    #pragma unroll
    for (int nf = 0; nf < 8; ++nf) {
      f32x4 z = {0.f, 0.f, 0.f, 0.f};
      acc[mf][nf] = z;
    }

  // ---- phase 2: K loop (20 iters of K=32); wave owns cols wid*128.. ----
  {
    const uint2* arow = ldsA + l16 * 81 + lg;
    const uint4* bp = (const uint4*)w2p8 + (size_t)lg * 512 + l16;
    for (int kq0 = 0; kq0 < 80; kq0 += 4) {
      U2L a[2];
      #pragma unroll
      for (int mf = 0; mf < 2; ++mf)
        a[mf].u = arow[mf * (16 * 81) + kq0];
      const uint4* bpi = bp + (size_t)kq0 * 512 + wid * 64;
      U4L2 q[4];
      q[0].u = bpi[0];                 // cols c0, nf 0,1
      q[1].u = bpi[16];                // cols c0, nf 2,3
      q[2].u = bpi[32];                // cols c1, nf 0,1
      q[3].u = bpi[48];                // cols c1, nf 2,3
      #pragma unroll
      for (int nf = 0; nf < 8; ++nf) {
        long long bl = q[nf >> 1].l[nf & 1];
        #pragma unroll
        for (int mf = 0; mf < 2; ++mf)
          acc[mf][nf] = __builtin_amdgcn_mfma_f32_16x16x32_fp8_fp8(
              a[mf].l, bl, acc[mf][nf], 0, 0, 0);
      }
    }
  }

  // ---- phase 3: fold b2 (permuted within each 64-col block), softmax ----
  {
    f32x4 b2v0 = *(const f32x4*)&b2[wid * 128 + l16 * 4];
    f32x4 b2v1 = *(const f32x4*)&b2[wid * 128 + 64 + l16 * 4];
    #pragma unroll
    for (int mf = 0; mf < 2; ++mf)
      #pragma unroll
      for (int nf = 0; nf < 8; ++nf) {
        float bv = (nf < 4) ? b2v0[nf] : b2v1[nf - 4];
        #pragma unroll
        for (int r = 0; r < 4; ++r)
          acc[mf][nf][r] += bv;
      }
  }

  #pragma unroll
  for (int mf = 0; mf < 2; ++mf)
    #pragma unroll
    for (int r = 0; r < 4; ++r) {
      float pm = -3.4e38f;
      #pragma unroll
      for (int nf = 0; nf < 8; ++nf) pm = fmaxf(pm, acc[mf][nf][r]);
      pm = fmaxf(pm, __shfl_xor(pm, 1));
      pm = fmaxf(pm, __shfl_xor(pm, 2));
      pm = fmaxf(pm, __shfl_xor(pm, 4));
      pm = fmaxf(pm, __shfl_xor(pm, 8));
      float s = 0.f;
      #pragma unroll
      for (int nf = 0; nf < 8; ++nf) s += __expf(acc[mf][nf][r] - pm);
      s += __shfl_xor(s, 1);
      s += __shfl_xor(s, 2);
      s += __shfl_xor(s, 4);
      s += __shfl_xor(s, 8);
      if (l16 == 0) {
        int row = mf * 16 + lg * 4 + r;    // 0..31
        red[wid][row][0] = pm;
        red[wid][row][1] = s;
      }
    }
  __syncthreads();

  if (tid < 32) {
    float M = -3.4e38f;
    #pragma unroll
    for (int w8 = 0; w8 < 8; ++w8) M = fmaxf(M, red[w8][tid][0]);
    float S = 0.f;
    #pragma unroll
    for (int w8 = 0; w8 < 8; ++w8)
      S += red[w8][tid][1] * __expf(red[w8][tid][0] - M);
    lzs[tid] = M + __logf(S);
  }
  __syncthreads();

  float* outb = out + ((size_t)(b * T_ + t) * U_ + uh * 32) * V_;
  #pragma unroll
  for (int mf = 0; mf < 2; ++mf)
    #pragma unroll
    for (int r = 0; r < 4; ++r) {
      int row = mf * 16 + lg * 4 + r;
      float lz = lzs[row];
      f32x4 o0, o1;
      o0[0] = acc[mf][0][r] - lz;
      o0[1] = acc[mf][1][r] - lz;
      o0[2] = acc[mf][2][r] - lz;
      o0[3] = acc[mf][3][r] - lz;
      o1[0] = acc[mf][4][r] - lz;
      o1[1] = acc[mf][5][r] - lz;
      o1[2] = acc[mf][6][r] - lz;
      o1[3] = acc[mf][7][r] - lz;
      float* orow = outb + (size_t)row * V_ + wid * 128 + l16 * 4;
      __builtin_nontemporal_store(o0, (f32x4*)orow);
      __builtin_nontemporal_store(o1, (f32x4*)(orow + 64));
    }
}

extern "C" void kernel_launch(void* const* d_in, const int* in_sizes, int n_in,
                              void* d_out, int out_size, void* d_ws, size_t ws_size,
                              hipStream_t stream) {
  const float* src = (const float*)d_in[0];
  const int*   slen = (const int*)d_in[1];
  const float* tgt = (const float*)d_in[2];
  const int*   tlen = (const int*)d_in[3];
  const float* W1 = (const float*)d_in[4];
  const float* b1 = (const float*)d_in[5];
  const float* W2 = (const float*)d_in[6];
  const float* b2 = (const float*)d_in[7];
  float* out = (float*)d_out;

  float* ps   = (float*)d_ws;                 // 512*640 f32
  float* pt   = ps + 512 * 640;               // 256*640 f32
  uint2* w2p8 = (uint2*)(pt + 256 * 640);     // 80*1024 uint2 (fp8 W2)

  k_prep<<<176, 640, 0, stream>>>(W2, w2p8, slen, tlen,
                                  out + (size_t)B_ * T_ * U_ * V_,
                                  src, tgt, W1, b1, ps, pt);
  k_joint<<<1024, 512, 0, stream>>>(ps, pt, w2p8, b2, out);
}